// Round 1
// baseline (227.851 us; speedup 1.0000x reference)
//
#include <hip/hip_runtime.h>

// RandomShiftsAug: the reference's grid_sample reduces exactly to an
// integer-pixel shift with replicate clamping:
//   out[n,c,oy,ox] = x[n,c, clamp(oy+sy-pad,0,H-1), clamp(ox+sx-pad,0,W-1)]
// (ix == ox + sx exactly; bilinear weights degenerate to {1,0}).
//
// R6: single experiment variable vs R5 (which was ~70us kernel time):
// 4 independent float4 elements per thread, phase-separated
// (addr-math+shift loads | 4 x-loads | selects | stores) to raise
// memory-level parallelism from 1 to 4 outstanding 16B loads per lane.
// Theory: R5 is latency-chain bound (shift load -> addr -> x load ->
// store, one load in flight), not BW bound (fills on this buffer hit
// 6.6 TB/s; R5 runs at ~3.7 TB/s effective). Plain stores kept: let the
// 130MB output land in L2/L3 and write back lazily (R4 showed forcing
// nt stores to HBM inside the kernel regresses).

#define NN 512
#define CC 9
#define HH 84
#define WW 84
#define W4 (WW / 4)                      // 21
#define ELEMS (NN * CC * HH * W4)        // 8,128,512 = 7938 * 1024 exactly
#define PER_THREAD 4
#define BLOCK 256

typedef float f4u __attribute__((ext_vector_type(4), aligned(4)));   // load, 4B-aligned
typedef float f4a __attribute__((ext_vector_type(4)));               // store, 16B-aligned

__device__ __forceinline__ float sel4(f4u w, int k) {
    return k == 0 ? w.x : (k == 1 ? w.y : (k == 2 ? w.z : w.w));
}

__global__ __launch_bounds__(256) void random_shift_kernel(
    const float* __restrict__ x,
    const int* __restrict__ shift,
    const int* __restrict__ pad_p,
    float* __restrict__ out)
{
    const int pad = pad_p[0];
    const int base = blockIdx.x * (BLOCK * PER_THREAD) + threadIdx.x;

    // Phase 1: index math + shift loads for all 4 elements (8 small loads
    // issue together; all hit L1/L2 after the first waves).
    int s_arr[PER_THREAD];
    int a_arr[PER_THREAD];
    const float* srcp[PER_THREAD];
    size_t dsto[PER_THREAD];

    #pragma unroll
    for (int k = 0; k < PER_THREAD; ++k) {
        int idx = base + k * BLOCK;
        int ox4 = idx % W4;
        int t   = idx / W4;
        int oy  = t % HH;
        int np  = t / HH;                  // n*CC + c (plane index)
        int n   = np / CC;

        // shift[n,0,0,0] = x-shift (width), shift[n,0,0,1] = y-shift (height)
        int sx = shift[2 * n + 0] - pad;
        int sy = shift[2 * n + 1] - pad;

        int sry = min(max(oy + sy, 0), HH - 1);
        int ox  = ox4 * 4;
        int s   = ox + sx;                 // window start in source row
        int a   = min(max(s, 0), WW - 4);  // clamped window start (interior: a==s)

        s_arr[k] = s;
        a_arr[k] = a;
        srcp[k]  = x + ((size_t)np * HH + sry) * WW + a;
        dsto[k]  = ((size_t)np * HH + oy) * WW + ox;
    }

    // Phase 2: issue all 4 main 16B loads back-to-back (MLP = 4).
    f4u w[PER_THREAD];
    #pragma unroll
    for (int k = 0; k < PER_THREAD; ++k)
        w[k] = *(const f4u*)srcp[k];

    // Phase 3: selects + stores.
    #pragma unroll
    for (int k = 0; k < PER_THREAD; ++k) {
        int s = s_arr[k];
        int a = a_arr[k];
        // element j wants src[clamp(s+j,0,W-1)] which lies in [a, a+3]
        int k0 = min(max(s + 0, 0), WW - 1) - a;
        int k1 = min(max(s + 1, 0), WW - 1) - a;
        int k2 = min(max(s + 2, 0), WW - 1) - a;
        int k3 = min(max(s + 3, 0), WW - 1) - a;

        f4a v;
        v.x = sel4(w[k], k0);
        v.y = sel4(w[k], k1);
        v.z = sel4(w[k], k2);
        v.w = sel4(w[k], k3);

        f4a* __restrict__ dst = (f4a*)(out + dsto[k]);
        *dst = v;                          // plain store: L2/L3-absorbed
    }
}

extern "C" void kernel_launch(void* const* d_in, const int* in_sizes, int n_in,
                              void* d_out, int out_size, void* d_ws, size_t ws_size,
                              hipStream_t stream)
{
    const float* x     = (const float*)d_in[0];
    const int*   shift = (const int*)d_in[1];
    const int*   pad   = (const int*)d_in[2];
    float*       out   = (float*)d_out;

    const int grid = ELEMS / (BLOCK * PER_THREAD);   // 7938, exact
    random_shift_kernel<<<grid, BLOCK, 0, stream>>>(x, shift, pad, out);
}

// Round 2
// 221.752 us; speedup vs baseline: 1.0275x; 1.0275x over previous
//
#include <hip/hip_runtime.h>

// RandomShiftsAug: the reference's grid_sample reduces exactly to an
// integer-pixel shift with replicate clamping:
//   out[n,c,oy,ox] = x[n,c, clamp(oy+sy-pad,0,H-1), clamp(ox+sx-pad,0,W-1)]
// (ix == ox + sx exactly; bilinear weights degenerate to {1,0}).
//
// R7: revert to the R5 structure (best measured: 222.6us total, kernel
// <77us). R6's MLP=4 phase-split experiment came back NEUTRAL-to-NEGATIVE
// (kernel ~80us, total 227.9us), falsifying the latency-chain theory.
// Standing theory: the kernel dispatch time (~70us) is pinned by
// co-running HBM traffic — the harness's two ~520MB poison fills leave
// the 256MB Infinity Cache full of dirty lines, and our kernel's
// compulsory 62MB fetch + 127MB write shares the HBM pipe with that
// drain: (194 + ~250MB)/6.3TB/s ~= 70us, matching every structural
// variant (R3~70, R5<77, R6~80). Kernel-side traffic is already
// minimal (each byte touched exactly once, coalesced float4 both ways,
// FETCH < input size due to L3 hits), so structure is not the lever.
// Plain stores (not nontemporal): R4 showed forcing writes to HBM
// inside the kernel regresses; let L2/L3 absorb and write back lazily.

#define NN 512
#define CC 9
#define HH 84
#define WW 84

typedef float f4u __attribute__((ext_vector_type(4), aligned(4)));   // load, 4B-aligned
typedef float f4a __attribute__((ext_vector_type(4)));               // store, 16B-aligned

__device__ __forceinline__ float sel4(f4u w, int k) {
    return k == 0 ? w.x : (k == 1 ? w.y : (k == 2 ? w.z : w.w));
}

__global__ __launch_bounds__(256) void random_shift_kernel(
    const float* __restrict__ x,
    const int* __restrict__ shift,
    const int* __restrict__ pad_p,
    float* __restrict__ out)
{
    const int pad = pad_p[0];
    const int W4 = WW / 4;                       // 21
    const int total = NN * CC * HH * W4;         // 8,128,512
    int idx = blockIdx.x * blockDim.x + threadIdx.x;
    if (idx >= total) return;

    int ox4 = idx % W4;
    int t   = idx / W4;
    int oy  = t % HH;
    int np  = t / HH;                            // n*CC + c (plane index)
    int n   = np / CC;

    // shift[n,0,0,0] = x-shift (width), shift[n,0,0,1] = y-shift (height)
    int sx = shift[2 * n + 0] - pad;
    int sy = shift[2 * n + 1] - pad;

    int sry = min(max(oy + sy, 0), HH - 1);
    const float* __restrict__ src =
        x + ((size_t)np * HH + sry) * WW;

    int ox = ox4 * 4;
    int s  = ox + sx;                 // window start in source row
    int a  = min(max(s, 0), WW - 4);  // clamped window start (interior: a==s)

    f4u w = *(const f4u*)(src + a);   // one 16B load, 4B-aligned

    // element j wants src[clamp(s+j,0,W-1)] which lies in [a, a+3]
    int k0 = min(max(s + 0, 0), WW - 1) - a;
    int k1 = min(max(s + 1, 0), WW - 1) - a;
    int k2 = min(max(s + 2, 0), WW - 1) - a;
    int k3 = min(max(s + 3, 0), WW - 1) - a;

    f4a v;
    v.x = sel4(w, k0);
    v.y = sel4(w, k1);
    v.z = sel4(w, k2);
    v.w = sel4(w, k3);

    f4a* __restrict__ dst =
        (f4a*)(out + ((size_t)np * HH + oy) * WW + ox);
    *dst = v;                          // plain store: L2/L3-absorbed
}

extern "C" void kernel_launch(void* const* d_in, const int* in_sizes, int n_in,
                              void* d_out, int out_size, void* d_ws, size_t ws_size,
                              hipStream_t stream)
{
    const float* x     = (const float*)d_in[0];
    const int*   shift = (const int*)d_in[1];
    const int*   pad   = (const int*)d_in[2];
    float*       out   = (float*)d_out;

    const int total  = NN * CC * HH * (WW / 4);
    const int block  = 256;
    const int grid   = (total + block - 1) / block;
    random_shift_kernel<<<grid, block, 0, stream>>>(x, shift, pad, out);
}